// Round 3
// baseline (256.043 us; speedup 1.0000x reference)
//
#include <hip/hip_runtime.h>
#include <math.h>

#define NB   8
#define NH   32
#define LQ   4
#define LK   4096
#define DD   128
#define SCALE_F 0.08838834764831845f
#define NWAVE 16
#define KPW   (LK / NWAVE)      // 256 keys per wave
#define NIT   (KPW / 2)         // 128 iterations, 2 keys per iteration
#define DEPTH 4                 // software-pipeline depth (iterations ahead)

// 256 blocks (one per (b,h)), 1024 threads = 16 waves, 16 waves/CU.
// Each wave owns 256 contiguous keys; per iteration it handles 2 keys
// (lanes 0-31 -> row j, lanes 32-63 -> row j+1), so each wave-level float4
// load is ONE contiguous 1 KB block. K/V loads run in a 4-deep rotating
// register pipeline (statically unrolled -> all indices compile-time), so
// ~8 KB/wave stays in flight to cover loaded-system HBM latency.
__global__ __launch_bounds__(1024, 4)
void attn_decode_kernel(const float* __restrict__ Q, const float* __restrict__ K,
                        const float* __restrict__ V, const float* __restrict__ Msk,
                        float* __restrict__ Out)
{
    __shared__ float o_buf[NWAVE][LQ][DD];   // 32 KB per-wave partial outputs
    __shared__ float ml_buf[NWAVE][LQ][2];

    const int bh   = blockIdx.x;             // 0..255
    const int b    = bh >> 5;                // H = 32
    const int tid  = threadIdx.x;
    const int wave = tid >> 6;               // 0..15
    const int lane = tid & 63;
    const int half = lane >> 5;              // which key of the pair
    const int sub  = lane & 31;              // d-slice: d0 = sub*4

    const float* qp = Q   + (size_t)bh * (LQ * DD);
    const float* kp = K   + (size_t)bh * (LK * DD);
    const float* vp = V   + (size_t)bh * (LK * DD);
    const float* mp = Msk + (size_t)b  * (LQ * LK);

    // Q fragment: lane holds q[qi][sub*4 .. sub*4+3]
    float4 q4[LQ];
#pragma unroll
    for (int qi = 0; qi < LQ; ++qi)
        q4[qi] = *(const float4*)(qp + qi * DD + sub * 4);

    float m_run[LQ], l_run[LQ];
    float4 o4[LQ];
#pragma unroll
    for (int qi = 0; qi < LQ; ++qi) {
        m_run[qi] = -INFINITY;
        l_run[qi] = 0.0f;
        o4[qi].x = o4[qi].y = o4[qi].z = o4[qi].w = 0.0f;
    }

    const int row0 = wave * KPW + half;      // this half's first key row
    const float* kbase = kp + (size_t)row0 * DD + sub * 4;
    const float* vbase = vp + (size_t)row0 * DD + sub * 4;
    // iteration t reads row row0 + 2t  ->  float offset t * 2*DD = t*256

    // pipeline prologue: fill DEPTH slots
    float4 kq[DEPTH], vq[DEPTH];
#pragma unroll
    for (int u = 0; u < DEPTH; ++u) {
        kq[u] = *(const float4*)(kbase + (size_t)u * 256);
        vq[u] = *(const float4*)(vbase + (size_t)u * 256);
    }

    for (int t = 0; t < NIT; t += DEPTH) {
#pragma unroll
        for (int u = 0; u < DEPTH; ++u) {
            const int it = t + u;
            // slot refill target (clamped at the end; duplicate loads are L1 hits
            // and their values are never consumed)
            const int tp = (it + DEPTH < NIT) ? (it + DEPTH) : (NIT - 1);

            // per-lane partial dot (consumes kq[u])
            float s[LQ];
#pragma unroll
            for (int qi = 0; qi < LQ; ++qi)
                s[qi] = kq[u].x * q4[qi].x + kq[u].y * q4[qi].y
                      + kq[u].z * q4[qi].z + kq[u].w * q4[qi].w;

            // refill K slot immediately (keeps the queue deep)
            kq[u] = *(const float4*)(kbase + (size_t)tp * 256);

            // reduce across the 32-lane half
#pragma unroll
            for (int msk = 1; msk <= 16; msk <<= 1) {
#pragma unroll
                for (int qi = 0; qi < LQ; ++qi)
                    s[qi] += __shfl_xor(s[qi], msk, 64);
            }

            const int jrow = wave * KPW + 2 * it + half;

            // online softmax update (consumes vq[u])
#pragma unroll
            for (int qi = 0; qi < LQ; ++qi) {
                const float sv = s[qi] * SCALE_F + mp[qi * LK + jrow];
                const float mn = fmaxf(m_run[qi], sv);
                const float f  = __expf(m_run[qi] - mn);
                const float p  = __expf(sv - mn);
                m_run[qi] = mn;
                l_run[qi] = l_run[qi] * f + p;
                o4[qi].x = o4[qi].x * f + p * vq[u].x;
                o4[qi].y = o4[qi].y * f + p * vq[u].y;
                o4[qi].z = o4[qi].z * f + p * vq[u].z;
                o4[qi].w = o4[qi].w * f + p * vq[u].w;
            }

            // refill V slot
            vq[u] = *(const float4*)(vbase + (size_t)tp * 256);
        }
    }

    // combine the two half-wave streams in-register (lanes l and l^32)
#pragma unroll
    for (int qi = 0; qi < LQ; ++qi) {
        const float m_o = __shfl_xor(m_run[qi], 32, 64);
        const float l_o = __shfl_xor(l_run[qi], 32, 64);
        float4 oo;
        oo.x = __shfl_xor(o4[qi].x, 32, 64);
        oo.y = __shfl_xor(o4[qi].y, 32, 64);
        oo.z = __shfl_xor(o4[qi].z, 32, 64);
        oo.w = __shfl_xor(o4[qi].w, 32, 64);
        const float M  = fmaxf(m_run[qi], m_o);
        const float fo = __expf(m_run[qi] - M);
        const float fx = __expf(m_o - M);
        o4[qi].x = o4[qi].x * fo + oo.x * fx;
        o4[qi].y = o4[qi].y * fo + oo.y * fx;
        o4[qi].z = o4[qi].z * fo + oo.z * fx;
        o4[qi].w = o4[qi].w * fo + oo.w * fx;
        l_run[qi] = l_run[qi] * fo + l_o * fx;
        m_run[qi] = M;
    }

    // stage per-wave partials to LDS
    if (half == 0) {
#pragma unroll
        for (int qi = 0; qi < LQ; ++qi)
            *(float4*)&o_buf[wave][qi][sub * 4] = o4[qi];
        if (sub == 0) {
#pragma unroll
            for (int qi = 0; qi < LQ; ++qi) {
                ml_buf[wave][qi][0] = m_run[qi];
                ml_buf[wave][qi][1] = l_run[qi];
            }
        }
    }
    __syncthreads();

    // final cross-wave combine: 512 threads, one (qi, d) each
    if (tid < LQ * DD) {
        const int qi = tid >> 7;
        const int d  = tid & 127;
        float M = -INFINITY;
#pragma unroll
        for (int w = 0; w < NWAVE; ++w)
            M = fmaxf(M, ml_buf[w][qi][0]);
        float Lsum = 0.0f, Osum = 0.0f;
#pragma unroll
        for (int w = 0; w < NWAVE; ++w) {
            const float f = __expf(ml_buf[w][qi][0] - M);
            Lsum += ml_buf[w][qi][1] * f;
            Osum += o_buf[w][qi][d] * f;
        }
        Out[(size_t)bh * (LQ * DD) + tid] = Osum / Lsum;
    }
}

extern "C" void kernel_launch(void* const* d_in, const int* in_sizes, int n_in,
                              void* d_out, int out_size, void* d_ws, size_t ws_size,
                              hipStream_t stream)
{
    const float* q   = (const float*)d_in[0];
    const float* k   = (const float*)d_in[1];
    const float* v   = (const float*)d_in[2];
    const float* msk = (const float*)d_in[3];
    float* out = (float*)d_out;

    attn_decode_kernel<<<dim3(NB * NH), dim3(1024), 0, stream>>>(q, k, v, msk, out);
}

// Round 4
// 188.745 us; speedup vs baseline: 1.3566x; 1.3566x over previous
//
#include <hip/hip_runtime.h>
#include <math.h>

#define NB   8
#define NH   32
#define LQ   4
#define LK   4096
#define DD   128
#define SCALE_F 0.08838834764831845f

// 256 blocks (one per (b,h)), 1024 threads = 16 waves.
// INTERLEAVED key mapping: at block step s, the 16 waves cover 64 CONSECUTIVE
// key rows (wave w -> rows s*64 + 4w .. 4w+3), so each block presents one
// sequential 2 MB stream per array to DRAM (512 streams device-wide) instead
// of 8192 distant per-wave slices. Online softmax is order-invariant, so the
// visit order change is free. Per-instruction coalescing unchanged: each
// wave-level float4 load is 1 KB contiguous (lanes 0-31 row j, 32-63 row j+1).
__global__ __launch_bounds__(1024, 4)
void attn_decode_kernel(const float* __restrict__ Q, const float* __restrict__ K,
                        const float* __restrict__ V, const float* __restrict__ Msk,
                        float* __restrict__ Out)
{
    __shared__ float o_buf[16][LQ][DD];   // 32 KB: per-wave partial outputs
    __shared__ float ml_buf[16][LQ][2];   // per-wave running (m, l)

    const int bh   = blockIdx.x;          // 0..255
    const int b    = bh >> 5;             // H = 32
    const int tid  = threadIdx.x;
    const int wave = tid >> 6;            // 0..15
    const int lane = tid & 63;
    const int half = lane >> 5;           // 0/1 : which key of the pair
    const int sub  = lane & 31;           // 0..31 : which float4 of the row

    const float* qp = Q   + (size_t)bh * (LQ * DD);
    const float* kp = K   + (size_t)bh * (LK * DD);
    const float* vp = V   + (size_t)bh * (LK * DD);
    const float* mp = Msk + (size_t)b  * (LQ * LK);

    // Q fragments: lane holds q[qi][sub*4 .. sub*4+3]
    float4 q4[LQ];
#pragma unroll
    for (int qi = 0; qi < LQ; ++qi)
        q4[qi] = *(const float4*)(qp + qi * DD + sub * 4);

    float m_run[LQ], l_run[LQ];
    float4 o4[LQ];
#pragma unroll
    for (int qi = 0; qi < LQ; ++qi) {
        m_run[qi] = -INFINITY;
        l_run[qi] = 0.0f;
        o4[qi].x = 0.0f; o4[qi].y = 0.0f; o4[qi].z = 0.0f; o4[qi].w = 0.0f;
    }

    for (int s = 0; s < 64; ++s) {
        const int base = s * 64 + wave * 4;   // this wave's 4 consecutive rows
        const int ja = base + half;           // half 0 -> row, half 1 -> row+1
        const int jb = ja + 2;

        // issue all 4 vector loads up front (4 KB / wave / iteration total)
        const float4 ka = *(const float4*)(kp + (size_t)ja * DD + sub * 4);
        const float4 kb = *(const float4*)(kp + (size_t)jb * DD + sub * 4);
        const float4 va = *(const float4*)(vp + (size_t)ja * DD + sub * 4);
        const float4 vb = *(const float4*)(vp + (size_t)jb * DD + sub * 4);

        // per-lane partial dot products
        float sa[LQ], sb[LQ];
#pragma unroll
        for (int qi = 0; qi < LQ; ++qi) {
            sa[qi] = ka.x*q4[qi].x + ka.y*q4[qi].y + ka.z*q4[qi].z + ka.w*q4[qi].w;
            sb[qi] = kb.x*q4[qi].x + kb.y*q4[qi].y + kb.z*q4[qi].z + kb.w*q4[qi].w;
        }
        // reduce across the 32-lane half (xor masks < 32 stay inside the half)
#pragma unroll
        for (int msk = 1; msk <= 16; msk <<= 1) {
#pragma unroll
            for (int qi = 0; qi < LQ; ++qi) {
                sa[qi] += __shfl_xor(sa[qi], msk, 64);
                sb[qi] += __shfl_xor(sb[qi], msk, 64);
            }
        }

        // online softmax update: one rescale per 2 keys
#pragma unroll
        for (int qi = 0; qi < LQ; ++qi) {
            const float s_a = sa[qi] * SCALE_F + mp[qi * LK + ja];
            const float s_b = sb[qi] * SCALE_F + mp[qi * LK + jb];
            const float mn  = fmaxf(m_run[qi], fmaxf(s_a, s_b));   // v_max3
            const float f   = __expf(m_run[qi] - mn);
            const float pa  = __expf(s_a - mn);
            const float pb  = __expf(s_b - mn);
            m_run[qi] = mn;
            l_run[qi] = l_run[qi] * f + pa + pb;
            o4[qi].x = o4[qi].x * f + pa * va.x + pb * vb.x;
            o4[qi].y = o4[qi].y * f + pa * va.y + pb * vb.y;
            o4[qi].z = o4[qi].z * f + pa * va.z + pb * vb.z;
            o4[qi].w = o4[qi].w * f + pa * va.w + pb * vb.w;
        }
    }

    // combine the two half-wave streams in-register (same dims, lanes l and l^32)
#pragma unroll
    for (int qi = 0; qi < LQ; ++qi) {
        const float m_o = __shfl_xor(m_run[qi], 32, 64);
        const float l_o = __shfl_xor(l_run[qi], 32, 64);
        float4 oo;
        oo.x = __shfl_xor(o4[qi].x, 32, 64);
        oo.y = __shfl_xor(o4[qi].y, 32, 64);
        oo.z = __shfl_xor(o4[qi].z, 32, 64);
        oo.w = __shfl_xor(o4[qi].w, 32, 64);
        const float M  = fmaxf(m_run[qi], m_o);
        const float fo = __expf(m_run[qi] - M);
        const float fx = __expf(m_o - M);
        o4[qi].x = o4[qi].x * fo + oo.x * fx;
        o4[qi].y = o4[qi].y * fo + oo.y * fx;
        o4[qi].z = o4[qi].z * fo + oo.z * fx;
        o4[qi].w = o4[qi].w * fo + oo.w * fx;
        l_run[qi] = l_run[qi] * fo + l_o * fx;
        m_run[qi] = M;
    }

    // stage per-wave partials to LDS
    if (half == 0) {
#pragma unroll
        for (int qi = 0; qi < LQ; ++qi)
            *(float4*)&o_buf[wave][qi][sub * 4] = o4[qi];
        if (sub == 0) {
#pragma unroll
            for (int qi = 0; qi < LQ; ++qi) {
                ml_buf[wave][qi][0] = m_run[qi];
                ml_buf[wave][qi][1] = l_run[qi];
            }
        }
    }
    __syncthreads();

    // final cross-wave combine: 512 threads, one (qi, d) each
    if (tid < LQ * DD) {
        const int qi = tid >> 7;
        const int d  = tid & 127;
        float M = -INFINITY;
#pragma unroll
        for (int w = 0; w < 16; ++w)
            M = fmaxf(M, ml_buf[w][qi][0]);
        float Lsum = 0.0f, Osum = 0.0f;
#pragma unroll
        for (int w = 0; w < 16; ++w) {
            const float f = __expf(ml_buf[w][qi][0] - M);
            Lsum += ml_buf[w][qi][1] * f;
            Osum += o_buf[w][qi][d] * f;
        }
        Out[(size_t)bh * (LQ * DD) + tid] = Osum / Lsum;
    }
}

extern "C" void kernel_launch(void* const* d_in, const int* in_sizes, int n_in,
                              void* d_out, int out_size, void* d_ws, size_t ws_size,
                              hipStream_t stream)
{
    const float* q   = (const float*)d_in[0];
    const float* k   = (const float*)d_in[1];
    const float* v   = (const float*)d_in[2];
    const float* msk = (const float*)d_in[3];
    float* out = (float*)d_out;

    attn_decode_kernel<<<dim3(NB * NH), dim3(1024), 0, stream>>>(q, k, v, msk, out);
}